// Round 5
// baseline (177.512 us; speedup 1.0000x reference)
//
#include <hip/hip_runtime.h>
#include <float.h>

#define NP 8192
#define WPB 2            // waves per block
#define BLK (WPB * 64)   // 128 threads
#define QPW 4            // queries per wave
#define QPB (WPB * QPW)  // 8 queries per block
#define PASSB (NP / QPB) // 1024 blocks per pass
#define CHUNK 1024       // candidates per LDS chunk (16 KB xyzw SoA)
#define CAP2 64          // survivor slots per query (expected ~11-25)

typedef unsigned long long u64;

// ws layout (floats):
//  0..3  *NP  pc1  x,y,z,w(|p|^2)
//  4..7  *NP  pc2  x,y,z,w
//  8..11 *NP  warp x,y,z,w
// 12..14 *NP  flow x,y,z
// 15..17 *NP  c2curv x,y,z
// 18..20 *NP  mcurv  x,y,z
// 21*NP      acc[0]=chamfer acc[1]=smooth acc[2]=curv

__device__ __forceinline__ float wavemin_f(float v) {
#pragma unroll
  for (int s = 1; s < 64; s <<= 1) v = fminf(v, __shfl_xor(v, s, 64));
  return v;
}

// score = |p|^2 - 2 p.q  (nq* = -2*q*); true d = score + |q|^2. Identical FMA
// sequence in scan1/scan2 so threshold compares are bitwise-consistent.
__device__ __forceinline__ float score1(float x, float y, float z, float w,
                                        float nx, float ny, float nz) {
  return fmaf(x, nx, fmaf(y, ny, fmaf(z, nz, w)));
}

// 128 threads stage CHUNK=1024 floats per array (2 float4 each)
__device__ __forceinline__ void stage4(const float* __restrict__ gx,
                                       const float* __restrict__ gy,
                                       const float* __restrict__ gz,
                                       const float* __restrict__ gw,
                                       float* sx, float* sy, float* sz, float* sw) {
  const int t = threadIdx.x * 4;
#pragma unroll
  for (int h = 0; h < CHUNK; h += 512) {
    *(float4*)(sx + t + h) = *(const float4*)(gx + t + h);
    *(float4*)(sy + t + h) = *(const float4*)(gy + t + h);
    *(float4*)(sz + t + h) = *(const float4*)(gz + t + h);
    *(float4*)(sw + t + h) = *(const float4*)(gw + t + h);
  }
}

// smallest remaining (s,j) across the wave; first-lane pick on exact float
// ties (prob ~0 on random data; tolerance covers it).
__device__ __forceinline__ void extract1f(float& s, int& j, int lane,
                                          float& od, int& oj) {
  float w = wavemin_f(s);
  u64 msk = __ballot(s == w);
  int src = (int)__ffsll(msk) - 1;
  oj = __shfl(j, src, 64);
  if (lane == src) s = FLT_MAX;
  od = w;
}

// Two-scan filter for QPW queries per wave.
// scan1: branchless per-lane min score. T[q] = K-th smallest of the 64
//   lane-minima (value knockout); the K knocked-out lanes own K distinct
//   candidates <= T so the global K-th smallest <= T.
// scan2: every score <= T[q] appended via LDS atomic counter; slots
//   pre-initialized to FLT_MAX so validity is data-derived.
template<int K>
__device__ __forceinline__ void wave_filter(const float* __restrict__ px,
                                            const float* __restrict__ py,
                                            const float* __restrict__ pz,
                                            const float* __restrict__ pw,
                                            const float (&nqx)[QPW],
                                            const float (&nqy)[QPW],
                                            const float (&nqz)[QPW],
                                            float* sx, float* sy, float* sz, float* sw,
                                            float (*hs)[CAP2], int (*hj)[CAP2],
                                            int* scnt) {
  const int lane = threadIdx.x & 63;
  float m[QPW];
#pragma unroll
  for (int q = 0; q < QPW; ++q) m[q] = FLT_MAX;

  // ---- scan 1 ----
  for (int c = 0; c < NP; c += CHUNK) {
    __syncthreads();
    stage4(px + c, py + c, pz + c, pw + c, sx, sy, sz, sw);
    __syncthreads();
#pragma unroll
    for (int g = 0; g < CHUNK; g += 256) {
      const int o = g + 4 * lane;
      float4 X = *(const float4*)(sx + o);
      float4 Y = *(const float4*)(sy + o);
      float4 Z = *(const float4*)(sz + o);
      float4 W = *(const float4*)(sw + o);
#pragma unroll
      for (int q = 0; q < QPW; ++q) {
        float s0 = score1(X.x, Y.x, Z.x, W.x, nqx[q], nqy[q], nqz[q]);
        float s1 = score1(X.y, Y.y, Z.y, W.y, nqx[q], nqy[q], nqz[q]);
        float s2 = score1(X.z, Y.z, Z.z, W.z, nqx[q], nqy[q], nqz[q]);
        float s3 = score1(X.w, Y.w, Z.w, W.w, nqx[q], nqy[q], nqz[q]);
        m[q] = fminf(m[q], fminf(fminf(s0, s1), fminf(s2, s3)));
      }
    }
  }

  // ---- threshold: K-th smallest lane-min via value knockout ----
  float T[QPW];
#pragma unroll
  for (int q = 0; q < QPW; ++q) {
    float mm = m[q], t = 0.f;
#pragma unroll
    for (int r = 0; r < K; ++r) {
      float w = wavemin_f(mm);
      u64 msk = __ballot(mm == w);
      if (lane == (int)__ffsll(msk) - 1) mm = FLT_MAX;
      t = w;
    }
    T[q] = t;
  }

  // ---- init survivor buffers (own wave's region only) ----
#pragma unroll
  for (int q = 0; q < QPW; ++q) {
    hs[q][lane] = FLT_MAX;
    hj[q][lane] = 0;
    if (lane == 0) scnt[q] = 0;
  }

  // ---- scan 2: collect all score <= T[q] ----
  for (int c = 0; c < NP; c += CHUNK) {
    __syncthreads();
    stage4(px + c, py + c, pz + c, pw + c, sx, sy, sz, sw);
    __syncthreads();
#pragma unroll
    for (int g = 0; g < CHUNK; g += 256) {
      const int o = g + 4 * lane;
      const int base = c + o;
      float4 X = *(const float4*)(sx + o);
      float4 Y = *(const float4*)(sy + o);
      float4 Z = *(const float4*)(sz + o);
      float4 W = *(const float4*)(sw + o);
#pragma unroll
      for (int q = 0; q < QPW; ++q) {
        float s0 = score1(X.x, Y.x, Z.x, W.x, nqx[q], nqy[q], nqz[q]);
        float s1 = score1(X.y, Y.y, Z.y, W.y, nqx[q], nqy[q], nqz[q]);
        float s2 = score1(X.z, Y.z, Z.z, W.z, nqx[q], nqy[q], nqz[q]);
        float s3 = score1(X.w, Y.w, Z.w, W.w, nqx[q], nqy[q], nqz[q]);
        float gm = fminf(fminf(s0, s1), fminf(s2, s3));
        if (__ballot(gm <= T[q]) != 0ULL) {
          if (s0 <= T[q]) { int p = atomicAdd(scnt + q, 1); if (p < CAP2) { hs[q][p] = s0; hj[q][p] = base + 0; } }
          if (s1 <= T[q]) { int p = atomicAdd(scnt + q, 1); if (p < CAP2) { hs[q][p] = s1; hj[q][p] = base + 1; } }
          if (s2 <= T[q]) { int p = atomicAdd(scnt + q, 1); if (p < CAP2) { hs[q][p] = s2; hj[q][p] = base + 2; } }
          if (s3 <= T[q]) { int p = atomicAdd(scnt + q, 1); if (p < CAP2) { hs[q][p] = s3; hj[q][p] = base + 3; } }
        }
      }
    }
  }
  __syncthreads();  // survivor writes visible before extraction
}

__global__ void k_prep(const float* __restrict__ pred, const float* __restrict__ gt,
                       const float* __restrict__ coords, float* __restrict__ ws) {
  int i = blockIdx.x * blockDim.x + threadIdx.x;
  if (i < NP) {
    float cx = coords[3 * i], cy = coords[3 * i + 1], cz = coords[3 * i + 2];
    float gx = gt[3 * i],     gy = gt[3 * i + 1],     gz = gt[3 * i + 2];
    float px = pred[3 * i],   py = pred[3 * i + 1],   pz = pred[3 * i + 2];
    float ax = cx + gx, ay = cy + gy, az = cz + gz;   // pc2
    float bx = cx + px, by = cy + py, bz = cz + pz;   // warp
    ws[0 * NP + i] = cx; ws[1 * NP + i] = cy; ws[2 * NP + i] = cz;
    ws[3 * NP + i] = cx * cx + cy * cy + cz * cz;
    ws[4 * NP + i] = ax; ws[5 * NP + i] = ay; ws[6 * NP + i] = az;
    ws[7 * NP + i] = ax * ax + ay * ay + az * az;
    ws[8 * NP + i] = bx; ws[9 * NP + i] = by; ws[10 * NP + i] = bz;
    ws[11 * NP + i] = bx * bx + by * by + bz * bz;
    ws[12 * NP + i] = px; ws[13 * NP + i] = py; ws[14 * NP + i] = pz;
  }
  if (i < 4) ws[21 * NP + i] = 0.f;
}

// fused: pass0 = pc2 x pc2 top-10 -> c2curv
//        pass1 = pc1 x pc1 top-10 -> mcurv + smooth
//        pass2 = pc2 x warp  min  -> chamfer dist2
__global__ __launch_bounds__(BLK, 4) void k_fused(float* __restrict__ ws) {
  __shared__ __align__(16) float sx[CHUNK], sy[CHUNK], sz[CHUNK], sw[CHUNK];
  __shared__ float hs[WPB][QPW][CAP2];
  __shared__ int hj[WPB][QPW][CAP2];
  __shared__ int scnt[WPB][QPW];
  __shared__ float red[WPB];
  const int pass = blockIdx.x % 3;
  const int pb = blockIdx.x / 3;
  const int wave = threadIdx.x >> 6, lane = threadIdx.x & 63;
  const int i0 = pb * QPB + wave * QPW;

  if (pass == 0) {
    const float* px = ws + 4 * NP; const float* py = ws + 5 * NP;
    const float* pz = ws + 6 * NP; const float* pw = ws + 7 * NP;
    float qx[QPW], qy[QPW], qz[QPW], nqx[QPW], nqy[QPW], nqz[QPW];
#pragma unroll
    for (int q = 0; q < QPW; ++q) {
      qx[q] = px[i0 + q]; qy[q] = py[i0 + q]; qz[q] = pz[i0 + q];
      nqx[q] = -2.f * qx[q]; nqy[q] = -2.f * qy[q]; nqz[q] = -2.f * qz[q];
    }
    wave_filter<10>(px, py, pz, pw, nqx, nqy, nqz, sx, sy, sz, sw,
                    hs[wave], hj[wave], scnt[wave]);
#pragma unroll
    for (int q = 0; q < QPW; ++q) {
      float s = hs[wave][q][lane]; int j = hj[wave][q][lane];
      float ax = 0.f, ay = 0.f, az = 0.f;
#pragma unroll
      for (int r = 0; r < 10; ++r) {
        float od; int oj;
        extract1f(s, j, lane, od, oj);
        ax += px[oj]; ay += py[oj]; az += pz[oj];
      }
      if (lane == 0) {
        const float inv9 = 1.f / 9.f;
        const int i = i0 + q;
        ws[15 * NP + i] = (ax - 10.f * qx[q]) * inv9;
        ws[16 * NP + i] = (ay - 10.f * qy[q]) * inv9;
        ws[17 * NP + i] = (az - 10.f * qz[q]) * inv9;
      }
    }
  } else if (pass == 1) {
    const float* px = ws + 0 * NP; const float* py = ws + 1 * NP;
    const float* pz = ws + 2 * NP; const float* pw = ws + 3 * NP;
    const float* wx = ws + 8 * NP; const float* wy = ws + 9 * NP;
    const float* wz = ws + 10 * NP;
    const float* fx = ws + 12 * NP; const float* fy = ws + 13 * NP;
    const float* fz = ws + 14 * NP;
    float nqx[QPW], nqy[QPW], nqz[QPW];
#pragma unroll
    for (int q = 0; q < QPW; ++q) {
      nqx[q] = -2.f * px[i0 + q]; nqy[q] = -2.f * py[i0 + q]; nqz[q] = -2.f * pz[i0 + q];
    }
    wave_filter<10>(px, py, pz, pw, nqx, nqy, nqz, sx, sy, sz, sw,
                    hs[wave], hj[wave], scnt[wave]);
    float smw = 0.f;
#pragma unroll
    for (int q = 0; q < QPW; ++q) {
      const int i = i0 + q;
      const float fix = fx[i], fiy = fy[i], fiz = fz[i];
      const float wix = wx[i], wiy = wy[i], wiz = wz[i];
      float s = hs[wave][q][lane]; int j = hj[wave][q][lane];
      float ax = 0.f, ay = 0.f, az = 0.f, sm = 0.f;
#pragma unroll
      for (int r = 0; r < 10; ++r) {
        float od; int oj;
        extract1f(s, j, lane, od, oj);
        ax += wx[oj]; ay += wy[oj]; az += wz[oj];
        if (r < 9) {
          float gx_ = fx[oj] - fix, gy_ = fy[oj] - fiy, gz_ = fz[oj] - fiz;
          sm += sqrtf(gx_ * gx_ + gy_ * gy_ + gz_ * gz_);
        }
      }
      smw += sm * 0.125f;
      if (lane == 0) {
        const float inv9 = 1.f / 9.f;
        ws[18 * NP + i] = (ax - 10.f * wix) * inv9;
        ws[19 * NP + i] = (ay - 10.f * wiy) * inv9;
        ws[20 * NP + i] = (az - 10.f * wiz) * inv9;
      }
    }
    if (lane == 0) red[wave] = smw;
    __syncthreads();
    if (threadIdx.x == 0) {
      float s = 0.f;
#pragma unroll
      for (int t = 0; t < WPB; ++t) s += red[t];
      atomicAdd(ws + 21 * NP + 1, s);
    }
  } else {
    // reverse chamfer: pc2 queries over warp candidates, min only
    const float* px = ws + 8 * NP; const float* py = ws + 9 * NP;
    const float* pz = ws + 10 * NP; const float* pw = ws + 11 * NP;
    const float* gx = ws + 4 * NP; const float* gy = ws + 5 * NP;
    const float* gz = ws + 6 * NP; const float* gw = ws + 7 * NP;
    float nqx[QPW], nqy[QPW], nqz[QPW], qw[QPW], m[QPW];
#pragma unroll
    for (int q = 0; q < QPW; ++q) {
      nqx[q] = -2.f * gx[i0 + q]; nqy[q] = -2.f * gy[i0 + q]; nqz[q] = -2.f * gz[i0 + q];
      qw[q] = gw[i0 + q];
      m[q] = FLT_MAX;
    }
    for (int c = 0; c < NP; c += CHUNK) {
      __syncthreads();
      stage4(px + c, py + c, pz + c, pw + c, sx, sy, sz, sw);
      __syncthreads();
#pragma unroll
      for (int g = 0; g < CHUNK; g += 256) {
        const int o = g + 4 * lane;
        float4 X = *(const float4*)(sx + o);
        float4 Y = *(const float4*)(sy + o);
        float4 Z = *(const float4*)(sz + o);
        float4 W = *(const float4*)(sw + o);
#pragma unroll
        for (int q = 0; q < QPW; ++q) {
          float s0 = score1(X.x, Y.x, Z.x, W.x, nqx[q], nqy[q], nqz[q]);
          float s1 = score1(X.y, Y.y, Z.y, W.y, nqx[q], nqy[q], nqz[q]);
          float s2 = score1(X.z, Y.z, Z.z, W.z, nqx[q], nqy[q], nqz[q]);
          float s3 = score1(X.w, Y.w, Z.w, W.w, nqx[q], nqy[q], nqz[q]);
          m[q] = fminf(m[q], fminf(fminf(s0, s1), fminf(s2, s3)));
        }
      }
    }
    float s = 0.f;
#pragma unroll
    for (int q = 0; q < QPW; ++q) s += wavemin_f(m[q]) + qw[q];
    if (lane == 0) red[wave] = s;
    __syncthreads();
    if (threadIdx.x == 0) {
      float t0 = 0.f;
#pragma unroll
      for (int t = 0; t < WPB; ++t) t0 += red[t];
      atomicAdd(ws + 21 * NP + 0, t0);
    }
  }
}

// warp x pc2 top-5 -> chamfer dist1 + interpolated-curvature loss
__global__ __launch_bounds__(BLK, 4) void k_cross(float* __restrict__ ws) {
  __shared__ __align__(16) float sx[CHUNK], sy[CHUNK], sz[CHUNK], sw[CHUNK];
  __shared__ float hs[WPB][QPW][CAP2];
  __shared__ int hj[WPB][QPW][CAP2];
  __shared__ int scnt[WPB][QPW];
  __shared__ float redc[WPB], redv[WPB];
  const float* px = ws + 4 * NP; const float* py = ws + 5 * NP;
  const float* pz = ws + 6 * NP; const float* pw = ws + 7 * NP;   // pc2 cands
  const float* wx = ws + 8 * NP; const float* wy = ws + 9 * NP;
  const float* wz = ws + 10 * NP; const float* ww = ws + 11 * NP; // warp queries
  const float* cx = ws + 15 * NP; const float* cy = ws + 16 * NP;
  const float* cz = ws + 17 * NP;                                 // c2curv
  const float* mx = ws + 18 * NP; const float* my = ws + 19 * NP;
  const float* mz = ws + 20 * NP;                                 // mcurv
  const int wave = threadIdx.x >> 6, lane = threadIdx.x & 63;
  const int i0 = blockIdx.x * QPB + wave * QPW;
  float nqx[QPW], nqy[QPW], nqz[QPW], qw[QPW];
#pragma unroll
  for (int q = 0; q < QPW; ++q) {
    nqx[q] = -2.f * wx[i0 + q]; nqy[q] = -2.f * wy[i0 + q]; nqz[q] = -2.f * wz[i0 + q];
    qw[q] = ww[i0 + q];
  }
  wave_filter<5>(px, py, pz, pw, nqx, nqy, nqz, sx, sy, sz, sw,
                 hs[wave], hj[wave], scnt[wave]);
  float csum = 0.f, vsum = 0.f;
#pragma unroll
  for (int q = 0; q < QPW; ++q) {
    const int i = i0 + q;
    float s = hs[wave][q][lane]; int j = hj[wave][q][lane];
    float wsum = 0.f, ix = 0.f, iy = 0.f, iz = 0.f, d1 = 0.f;
#pragma unroll
    for (int r = 0; r < 5; ++r) {
      float od; int oj;
      extract1f(s, j, lane, od, oj);
      float d = od + qw[q];           // true squared distance
      if (r == 0) d1 = d;
      float wt = 1.f / (d + 1e-8f);
      wsum += wt;
      ix += wt * cx[oj]; iy += wt * cy[oj]; iz += wt * cz[oj];
    }
    float inv = 1.f / wsum;
    float ex = ix * inv - mx[i];
    float ey = iy * inv - my[i];
    float ez = iz * inv - mz[i];
    csum += d1;
    vsum += ex * ex + ey * ey + ez * ez;
  }
  if (lane == 0) { redc[wave] = csum; redv[wave] = vsum; }
  __syncthreads();
  if (threadIdx.x == 0) {
    float sc = 0.f, sv = 0.f;
#pragma unroll
    for (int t = 0; t < WPB; ++t) { sc += redc[t]; sv += redv[t]; }
    atomicAdd(ws + 21 * NP + 0, sc);
    atomicAdd(ws + 21 * NP + 2, sv);
  }
}

__global__ void k_final(const float* __restrict__ ws, float* __restrict__ out) {
  float ch = ws[21 * NP + 0];
  float sm = ws[21 * NP + 1];
  float cv = ws[21 * NP + 2];
  out[0] = 0.02f * ch + 0.02f * 0.3f * cv + 0.02f * sm;
}

extern "C" void kernel_launch(void* const* d_in, const int* in_sizes, int n_in,
                              void* d_out, int out_size, void* d_ws, size_t ws_size,
                              hipStream_t stream) {
  (void)in_sizes; (void)n_in; (void)out_size; (void)ws_size;
  const float* pred   = (const float*)d_in[0];
  const float* gt     = (const float*)d_in[1];
  const float* coords = (const float*)d_in[2];
  float* ws  = (float*)d_ws;
  float* out = (float*)d_out;

  k_prep<<<dim3((NP + BLK - 1) / BLK), dim3(BLK), 0, stream>>>(pred, gt, coords, ws);
  k_fused<<<dim3(3 * PASSB), dim3(BLK), 0, stream>>>(ws);
  k_cross<<<dim3(PASSB), dim3(BLK), 0, stream>>>(ws);
  k_final<<<1, 1, 0, stream>>>(ws, out);
}